// Round 2
// baseline (102.080 us; speedup 1.0000x reference)
//
#include <hip/hip_runtime.h>
#include <math.h>

#define BS 16
#define NPTS 2048
#define MPTS 2048
#define KSEG 32
#define DDIM 128

#define NTILE 16           // point tiles per batch
#define PPB 128            // points per block (NPTS / NTILE)

// ws float layout (no zero-init needed: OFF_CNT is zeroed by cham_seg_kernel
// each launch, stream-ordered before loss_kernel's atomics; everything else
// is written before it is read within the same launch)
#define OFF_SEGP  0                        // 3 * BS * NTILE * KSEG = 24576 floats
#define OFF_LOSSP 24576                    // 64 floats (32 totals + 32 counts)
#define OFF_CNT   24640                    // 1 int (last-block counter)

// grid 256 = b(16) x tile(16).  Block 512 thr = 8 waves; all M=2048 deformed
// points staged once in LDS as {y, 0.5|y|^2}; (wave w, half h) scans m-slice
// s = 2w+h of 128 m for 4 points/lane (p = 32j + ll).  Block finalizes cham
// for its 128 points in LDS, then computes the per-tile segment partial sums
// (seg2def / sup_p / sup_f) directly -- no part/xn global round-trip.
__global__ __launch_bounds__(512) void cham_seg_kernel(
    const float* __restrict__ pc_partial, const float* __restrict__ deformed,
    const float* __restrict__ p_rot, const float* __restrict__ p_t,
    const float* __restrict__ f_rot, const float* __restrict__ f_t,
    const float* __restrict__ tg_rot, const float* __restrict__ tg_t,
    const float* __restrict__ sr_rot, const float* __restrict__ sr_t,
    const float* __restrict__ seg_p, const float* __restrict__ seg_f,
    float* __restrict__ ws)
{
    __shared__ union {
        float4 y[2048];          // 32 KB  (phase 1: staged deformed points)
        float  red[3][2048];     // 24 KB  (phase 2: seg reduction scratch)
    } sm;
    __shared__ float pmin[16][PPB];   // 8 KB
    __shared__ float xnLDS[PPB];
    __shared__ float chamLDS[PPB];

    const int bid  = blockIdx.x;
    const int b    = bid >> 4;
    const int tile = bid & 15;
    const int t  = threadIdx.x;
    const int l  = t & 63;
    const int w  = t >> 6;        // wave 0..7
    const int h  = l >> 5;        // half-wave
    const int ll = l & 31;
    const int s  = w * 2 + h;     // m-slice 0..15 (128 m each)

    if (bid == 0 && t == 0) ((int*)ws)[OFF_CNT] = 0;   // for loss last-block

    // stage all 2048 m as {y, 0.5*|y|^2} (coalesced, overlaps xform math)
    const float* def0 = deformed + (size_t)b * 3 * MPTS;
#pragma unroll
    for (int i = 0; i < 4; i++) {
        int m = i * 512 + t;
        float y0 = def0[m], y1 = def0[MPTS + m], y2 = def0[2*MPTS + m];
        sm.y[m] = make_float4(y0, y1, y2, 0.5f*(y0*y0 + y1*y1 + y2*y2));
    }

    // fold the 5-transform chain into one affine (row-vector convention):
    // x = p @ R + T, R = ((P @ Tg^T) @ Sr) @ F^T,
    // T = (((p_t - tg_t) @ Tg^T) @ Sr + sr_t - f_t) @ F^T
    float R[9], T[3];
    {
        float P[9], F[9], Tg[9], Sr[9];
#pragma unroll
        for (int i = 0; i < 9; i++) {
            P[i] = p_rot[b*9+i];  F[i] = f_rot[b*9+i];
            Tg[i] = tg_rot[b*9+i]; Sr[i] = sr_rot[b*9+i];
        }
        float A[9], Bm[9];
#pragma unroll
        for (int i = 0; i < 3; i++)
#pragma unroll
            for (int j = 0; j < 3; j++)
                A[i*3+j] = P[i*3+0]*Tg[j*3+0] + P[i*3+1]*Tg[j*3+1] + P[i*3+2]*Tg[j*3+2];
#pragma unroll
        for (int i = 0; i < 3; i++)
#pragma unroll
            for (int j = 0; j < 3; j++)
                Bm[i*3+j] = A[i*3+0]*Sr[0*3+j] + A[i*3+1]*Sr[1*3+j] + A[i*3+2]*Sr[2*3+j];
#pragma unroll
        for (int i = 0; i < 3; i++)
#pragma unroll
            for (int j = 0; j < 3; j++)
                R[i*3+j] = Bm[i*3+0]*F[j*3+0] + Bm[i*3+1]*F[j*3+1] + Bm[i*3+2]*F[j*3+2];
        float t0[3], t1[3], t2[3], t3[3];
#pragma unroll
        for (int i = 0; i < 3; i++) t0[i] = p_t[b*3+i] - tg_t[b*3+i];
#pragma unroll
        for (int j = 0; j < 3; j++)
            t1[j] = t0[0]*Tg[j*3+0] + t0[1]*Tg[j*3+1] + t0[2]*Tg[j*3+2];
#pragma unroll
        for (int j = 0; j < 3; j++)
            t2[j] = t1[0]*Sr[0*3+j] + t1[1]*Sr[1*3+j] + t1[2]*Sr[2*3+j];
#pragma unroll
        for (int i = 0; i < 3; i++) t3[i] = t2[i] + sr_t[b*3+i] - f_t[b*3+i];
#pragma unroll
        for (int j = 0; j < 3; j++)
            T[j] = t3[0]*F[j*3+0] + t3[1]*F[j*3+1] + t3[2]*F[j*3+2];
    }

    // transform this block's 128 points: 4 per lane (p = 32j + ll),
    // replicated across waves (each wave scans a different m-slice)
    const int n0 = tile * PPB;
    const float* pcb = pc_partial + (size_t)b * NPTS * 3;
    float x0[4], x1[4], x2[4], xn[4], mn[4];
#pragma unroll
    for (int j = 0; j < 4; j++) {
        const float* pc = pcb + (size_t)(n0 + ll + 32*j) * 3;
        float px = pc[0], py = pc[1], pz = pc[2];
        x0[j] = px*R[0] + py*R[3] + pz*R[6] + T[0];
        x1[j] = px*R[1] + py*R[4] + pz*R[7] + T[1];
        x2[j] = px*R[2] + py*R[5] + pz*R[8] + T[2];
        xn[j] = x0[j]*x0[j] + x1[j]*x1[j] + x2[j]*x2[j];
        mn[j] = 3.402823466e+38f;
    }
    if (t < 32) {            // w==0, h==0: one copy of xn into LDS
#pragma unroll
        for (int j = 0; j < 4; j++) xnLDS[ll + 32*j] = xn[j];
    }
    __syncthreads();

    // scan my 128-m slice: score = 0.5|y|^2 - x.y ; track min
    const float4* yb = sm.y + s * 128;
#pragma unroll 4
    for (int i = 0; i < 128; i++) {
        float4 y = yb[i];                 // 2-address broadcast per wave
#pragma unroll
        for (int j = 0; j < 4; j++) {
            float sc = fmaf(-x2[j], y.z, fmaf(-x1[j], y.y, fmaf(-x0[j], y.x, y.w)));
            mn[j] = fminf(mn[j], sc);
        }
    }
#pragma unroll
    for (int j = 0; j < 4; j++) pmin[s][ll + 32*j] = mn[j];
    __syncthreads();

    // finalize cham for the 128 points (min over 16 slices)
    if (t < PPB) {
        float v = pmin[0][t];
#pragma unroll
        for (int q = 1; q < 16; q++) v = fminf(v, pmin[q][t]);
        chamLDS[t] = fmaxf(fmaf(2.0f, v, xnLDS[t]), 0.0f);
    }
    __syncthreads();

    // per-tile segment partials over the 128 rows.  wave w covers rows
    // [w*16, w*16+16): lane l -> rowoff=l>>3, k4=l&7; float4 loads give
    // 1 KB contiguous per wave-instr.
    const int rowoff = l >> 3;
    const int k4 = l & 7;
    const float4* sp4 = (const float4*)(seg_p + ((size_t)b * NPTS + n0) * KSEG);
    const float4* sf4 = (const float4*)(seg_f + ((size_t)b * NPTS + n0) * KSEG);
    float4 ap = make_float4(0.f,0.f,0.f,0.f);
    float4 af = make_float4(0.f,0.f,0.f,0.f);
    float4 a2 = make_float4(0.f,0.f,0.f,0.f);
#pragma unroll
    for (int i = 0; i < 2; i++) {
        int n = w * 16 + i * 8 + rowoff;
        float c = chamLDS[n];             // 8-lane broadcast
        float4 vp = sp4[n * 8 + k4];
        float4 vf = sf4[n * 8 + k4];
        ap.x += vp.x; ap.y += vp.y; ap.z += vp.z; ap.w += vp.w;
        af.x += vf.x; af.y += vf.y; af.z += vf.z; af.w += vf.w;
        a2.x = fmaf(vp.x, c, a2.x); a2.y = fmaf(vp.y, c, a2.y);
        a2.z = fmaf(vp.z, c, a2.z); a2.w = fmaf(vp.w, c, a2.w);
    }
    // layout so red[j*32 + k] (j = w*8+rowoff, 0..63) is the partial for seg k
    sm.red[0][t*4+0] = ap.x; sm.red[0][t*4+1] = ap.y; sm.red[0][t*4+2] = ap.z; sm.red[0][t*4+3] = ap.w;
    sm.red[1][t*4+0] = af.x; sm.red[1][t*4+1] = af.y; sm.red[1][t*4+2] = af.z; sm.red[1][t*4+3] = af.w;
    sm.red[2][t*4+0] = a2.x; sm.red[2][t*4+1] = a2.y; sm.red[2][t*4+2] = a2.z; sm.red[2][t*4+3] = a2.w;
    __syncthreads();

    if (t < KSEG) {
        float s0 = 0.f, s1 = 0.f, s2 = 0.f;
#pragma unroll
        for (int j = 0; j < 64; j++) {
            s0 += sm.red[0][j*32 + t];
            s1 += sm.red[1][j*32 + t];
            s2 += sm.red[2][j*32 + t];
        }
        // segpart[x][b][tile][k]
        ws[OFF_SEGP + ((0*BS + b)*NTILE + tile)*KSEG + t] = s0;
        ws[OFF_SEGP + ((1*BS + b)*NTILE + tile)*KSEG + t] = s1;
        ws[OFF_SEGP + ((2*BS + b)*NTILE + tile)*KSEG + t] = s2;
    }
}

// grid: BS*2 blocks; block handles 16 (b,k) cells, 16 threads per cell over D.
// Writes per-block (total, count) partials; the LAST block (device-scope
// counter, canonical threadfence reduction pattern) folds the final reduce
// and writes the scalar output -- no separate final kernel.
__global__ __launch_bounds__(256) void loss_kernel(
    const float* __restrict__ rf_tok, const float* __restrict__ rp_tok,
    float* __restrict__ ws, float* __restrict__ out)
{
    const int b  = blockIdx.x >> 1;
    const int kh = blockIdx.x & 1;
    const int t = threadIdx.x;
    const int cell = t >> 4;   // 0..15
    const int dg   = t & 15;
    const int k = kh * 16 + cell;

    // sum the 16 per-tile partials (same-address broadcast loads, L2-hot)
    float supp = 0.f, supf = 0.f;
#pragma unroll
    for (int nc = 0; nc < NTILE; nc++) {
        supp += ws[OFF_SEGP + ((0*BS + b)*NTILE + nc)*KSEG + k];
        supf += ws[OFF_SEGP + ((1*BS + b)*NTILE + nc)*KSEG + k];
    }
    const float spv = fmaxf(supp, 1.0f);
    const float sfv = fmaxf(supf, 1.0f);

    const float* rf = rf_tok + ((size_t)b * KSEG + k) * DDIM;
    const float* rp = rp_tok + ((size_t)b * KSEG + k) * DDIM;
    float acc = 0.f;
#pragma unroll
    for (int j = 0; j < 8; j++) {
        int d = dg + 16 * j;
        float v = rf[d] / sfv - rp[d] / spv;
        acc += v * v;
    }
#pragma unroll
    for (int off = 8; off; off >>= 1) acc += __shfl_xor(acc, off);

    __shared__ float lbuf[16], cbuf[16];
    if (dg == 0) {
        float s2d = 0.f;
#pragma unroll
        for (int nc = 0; nc < NTILE; nc++)
            s2d += ws[OFF_SEGP + ((2*BS + b)*NTILE + nc)*KSEG + k];
        bool valid = (supp >= 20.0f) && (supf >= 20.0f);
        float arg = s2d / spv / 0.05f;
        float rel = 1.0f / (1.0f + expf(-arg));
        float ld = acc - rel; ld = ld * ld;
        bool msk = valid && (ld <= 20.0f);
        lbuf[cell] = msk ? ld : 0.0f;
        cbuf[cell] = msk ? 1.0f : 0.0f;
    }
    __syncthreads();

    __shared__ int isLast;
    if (t == 0) {
        float st = 0.f, sc = 0.f;
#pragma unroll
        for (int i = 0; i < 16; i++) { st += lbuf[i]; sc += cbuf[i]; }
        ws[OFF_LOSSP + blockIdx.x]      = st;
        ws[OFF_LOSSP + 32 + blockIdx.x] = sc;
        __threadfence();                              // release partials
        int prev = atomicAdd((int*)ws + OFF_CNT, 1);  // device-scope
        isLast = (prev == 31) ? 1 : 0;
    }
    __syncthreads();

    if (isLast) {
        __threadfence();                              // acquire others' writes
        float v1 = 0.f, v2 = 0.f;
        if (t < 32) {
            v1 = __hip_atomic_load(ws + OFF_LOSSP + t,
                                   __ATOMIC_RELAXED, __HIP_MEMORY_SCOPE_AGENT);
            v2 = __hip_atomic_load(ws + OFF_LOSSP + 32 + t,
                                   __ATOMIC_RELAXED, __HIP_MEMORY_SCOPE_AGENT);
        }
#pragma unroll
        for (int off = 16; off; off >>= 1) {
            v1 += __shfl_xor(v1, off);
            v2 += __shfl_xor(v2, off);
        }
        if (t == 0) out[0] = v1 / (v2 + 1.0f) * 1.0f;  // WEIGHT = 1.0
    }
}

extern "C" void kernel_launch(void* const* d_in, const int* in_sizes, int n_in,
                              void* d_out, int out_size, void* d_ws, size_t ws_size,
                              hipStream_t stream) {
    const float* r_tokens_full    = (const float*)d_in[0];
    const float* r_tokens_partial = (const float*)d_in[1];
    const float* pc_seg_partial   = (const float*)d_in[2];
    const float* pc_seg_full      = (const float*)d_in[3];
    const float* pc_partial       = (const float*)d_in[4];
    const float* deformed         = (const float*)d_in[5];
    const float* p_rot            = (const float*)d_in[6];
    const float* p_t              = (const float*)d_in[7];
    const float* f_rot            = (const float*)d_in[8];
    const float* f_t              = (const float*)d_in[9];
    const float* tgt_rand_rot     = (const float*)d_in[10];
    const float* tgt_rand_t       = (const float*)d_in[11];
    const float* src_rand_rot     = (const float*)d_in[12];
    const float* src_rand_t       = (const float*)d_in[13];

    float* ws  = (float*)d_ws;
    float* out = (float*)d_out;

    cham_seg_kernel<<<BS * NTILE, 512, 0, stream>>>(
        pc_partial, deformed, p_rot, p_t, f_rot, f_t,
        tgt_rand_rot, tgt_rand_t, src_rand_rot, src_rand_t,
        pc_seg_partial, pc_seg_full, ws);

    loss_kernel<<<BS * 2, 256, 0, stream>>>(
        r_tokens_full, r_tokens_partial, ws, out);
}